// Round 14
// baseline (1572.781 us; speedup 1.0000x reference)
//
#include <hip/hip_runtime.h>
#include <hip/hip_cooperative_groups.h>
#include <cmath>

namespace cg = cooperative_groups;

// ConvLSTM, single cooperative kernel (512 blocks x 256 thr, 2 blocks/CU
// residency margin; R13's 1024-block version was rejected by the
// cooperative-launch capacity check and never ran).
//   Phase A: xg = conv_same(x[:, ::-1], Wx); 4 slab-tasks per block,
//            R12's depth-1 A/B register pipeline.
//   Phase B: 16 LSTM steps with grid.sync() between; c-state in registers
//            (c0,c1); block owns 2 adjacent rows (shared h halo loads).
//            Group blk&7==b produces AND consumes image b -> locality.
//
// x:  (B=8, T=16, C=16, H=128, W=128) f32
// Wx: (KH=4, KW=2, C=16, O=8) HWIO     idx = kh*256 + kw*128 + c*8 + o
// Wh: (KH=4, KW=2, F=2, O=8)
// out:(B, T, F=2, H, W) f32
// ws: xg (64 MiB, layout [t][b][o][h][w])

constexpr int B_ = 8;
constexpr int T_ = 16;
constexpr int C_ = 16;
constexpr int F_ = 2;
constexpr int O_ = 8;
constexpr int H_ = 128;
constexpr int W_ = 128;
constexpr int HW_ = H_ * W_;
constexpr int KH_ = 4;
constexpr int KW_ = 2;
constexpr int PX_ = 4;

typedef float fv4 __attribute__((ext_vector_type(4)));

__device__ __forceinline__ float hsig(float z) {
    return fminf(fmaxf(0.2f * z + 0.5f, 0.0f), 1.0f);
}

__device__ __forceinline__ float ftanh(float x) {
    float e = __expf(2.0f * x);
    return fmaf(-2.0f, 1.0f / (e + 1.0f), 1.0f);
}

template<bool CHECK>
__device__ __forceinline__ void load4(
    const float* __restrict__ xc, int r0m1, fv4 a[KH_])
{
    #pragma unroll
    for (int rr = 0; rr < KH_; ++rr) {
        int ih = r0m1 + rr;
        if (CHECK) {
            bool v = (unsigned)ih < (unsigned)H_;
            a[rr] = *reinterpret_cast<const fv4*>(xc + (v ? ih : 0) * W_);
            if (!v) a[rr] = (fv4)0.0f;
        } else {
            a[rr] = *reinterpret_cast<const fv4*>(xc + ih * W_);
        }
    }
}

__device__ __forceinline__ void accum4(
    const float* __restrict__ wc,
    const fv4 a[KH_], float acc[PX_][O_], bool cval)
{
    #pragma unroll
    for (int kh = 0; kh < KH_; ++kh) {
        float x4 = __shfl_down(a[kh].x, 1, 64);
        x4 = cval ? x4 : 0.0f;
        const float* wp = wc + kh * (KW_ * C_ * O_);
        #pragma unroll
        for (int o = 0; o < O_; ++o) {
            float w0 = wp[o];
            float w1 = wp[C_ * O_ + o];
            acc[0][o] = fmaf(a[kh].x, w0, acc[0][o]);
            acc[1][o] = fmaf(a[kh].y, w0, acc[1][o]);
            acc[2][o] = fmaf(a[kh].z, w0, acc[2][o]);
            acc[3][o] = fmaf(a[kh].w, w0, acc[3][o]);
            acc[0][o] = fmaf(a[kh].y, w1, acc[0][o]);
            acc[1][o] = fmaf(a[kh].z, w1, acc[1][o]);
            acc[2][o] = fmaf(a[kh].w, w1, acc[2][o]);
            acc[3][o] = fmaf(x4,      w1, acc[3][o]);
        }
    }
}

template<bool CHECK>
__device__ __forceinline__ void conv_pipe(
    const float* __restrict__ xb, const float* __restrict__ Wx,
    int r0m1, bool cval, float acc[PX_][O_])
{
    fv4 A[KH_], Bv[KH_];
    load4<CHECK>(xb, r0m1, A);
    #pragma unroll 1
    for (int cc = 0; cc < C_ - 2; cc += 2) {
        load4<CHECK>(xb + (cc + 1) * HW_, r0m1, Bv);
        accum4(Wx + cc * O_, A, acc, cval);
        load4<CHECK>(xb + (cc + 2) * HW_, r0m1, A);
        accum4(Wx + (cc + 1) * O_, Bv, acc, cval);
    }
    load4<CHECK>(xb + (C_ - 1) * HW_, r0m1, Bv);
    accum4(Wx + (C_ - 2) * O_, A, acc, cval);
    accum4(Wx + (C_ - 1) * O_, Bv, acc, cval);
}

// one xg slab-task (wid in 0..2047)
__device__ __forceinline__ void xg_task(
    const float* __restrict__ x, const float* __restrict__ Wx,
    float* __restrict__ xg, int wid, int tid)
{
    int bt   = wid >> 4;
    int slab = wid & 15;

    int oh_l = tid >> 5;
    int q    = tid & 31;
    int ow4  = q << 2;

    int r0 = slab * 8 + oh_l;

    int b    = bt >> 4;
    int trev = bt & 15;
    int t    = 15 - trev;

    const float* xb = x + (size_t)bt * C_ * HW_ + ow4;
    bool cval = ow4 < (W_ - 4);

    float acc[PX_][O_];
    #pragma unroll
    for (int p = 0; p < PX_; ++p)
        #pragma unroll
        for (int o = 0; o < O_; ++o) acc[p][o] = 0.0f;

    if (slab >= 1 && slab <= 14) {
        conv_pipe<false>(xb, Wx, r0 - 1, cval, acc);
    } else {
        conv_pipe<true>(xb, Wx, r0 - 1, cval, acc);
    }

    float* dst = xg + (size_t)(t * B_ + b) * O_ * HW_ + r0 * W_ + ow4;
    #pragma unroll
    for (int o = 0; o < O_; ++o) {
        fv4 s;
        s.x = acc[0][o]; s.y = acc[1][o]; s.z = acc[2][o]; s.w = acc[3][o];
        *reinterpret_cast<fv4*>(dst + o * HW_) = s;
    }
}

// grid: 512 blocks x 256 threads, cooperative (2 blocks/CU margin).
__global__ __launch_bounds__(256, 2) void fused_kernel(
    const float* __restrict__ x,
    const float* __restrict__ Wx,
    const float* __restrict__ Wh,
    float* __restrict__ out,
    float* __restrict__ xg)
{
    cg::grid_group grid = cg::this_grid();
    int tid = threadIdx.x;

    // ---- Phase A: 4 slab-tasks per block; group blk&7 owns image b=blk&7.
    {
        int base = (blockIdx.x & 7) * 256 + (blockIdx.x >> 3) * 4;
        #pragma unroll 1
        for (int k = 0; k < 4; ++k)
            xg_task(x, Wx, xg, base + k, tid);
    }

    __threadfence();
    grid.sync();

    // ---- Phase B: 16 LSTM steps; block = (b, row-pair oh0..oh0+1).
    int f   = tid >> 7;               // wave-uniform
    int ow  = tid & 127;
    int b   = blockIdx.x & 7;
    int oh0 = (blockIdx.x >> 3) << 1; // 0,2,..,126

    bool cv  = (ow + 1) < W_;
    int  co1 = cv ? 1 : 0;

    float c0 = 0.0f, c1 = 0.0f;

    #pragma unroll 1
    for (int t = 0; t < T_; ++t) {
        if (t > 0) {
            __threadfence();
            grid.sync();
        }

        const float* xgp = xg + ((size_t)(t * B_ + b) * O_ + f) * HW_
                              + oh0 * W_ + ow;
        float ai0 = xgp[0],        ai1 = xgp[W_];
        float af0 = xgp[2 * HW_],  af1 = xgp[2 * HW_ + W_];
        float ag0 = xgp[4 * HW_],  ag1 = xgp[4 * HW_ + W_];
        float ao0 = xgp[6 * HW_],  ao1 = xgp[6 * HW_ + W_];

        if (t > 0) {
            const float* hs = out + (size_t)(b * T_ + (t - 1)) * F_ * HW_;
            #pragma unroll
            for (int fin = 0; fin < F_; ++fin) {
                float h0v[5], h1v[5];     // rows oh0-1 .. oh0+3 (shared)
                #pragma unroll
                for (int rr = 0; rr < 5; ++rr) {
                    int ih  = oh0 - 1 + rr;
                    bool rv = (unsigned)ih < (unsigned)H_;
                    const float* hrow = hs + fin * HW_ + (rv ? ih : 0) * W_ + ow;
                    float h0 = hrow[0], h1 = hrow[co1];
                    h0v[rr] = rv ? h0 : 0.0f;
                    h1v[rr] = (rv && cv) ? h1 : 0.0f;
                }
                #pragma unroll
                for (int kh = 0; kh < KH_; ++kh) {
                    // Wh idx = kh*32 + kw*16 + fin*8 + o; o = {f,2+f,4+f,6+f}
                    const float* wb = Wh + kh * (KW_ * F_ * O_) + fin * O_ + f;
                    float wi0 = wb[0],  wi1 = wb[16];
                    float wf0 = wb[2],  wf1 = wb[18];
                    float wg0 = wb[4],  wg1 = wb[20];
                    float wo0 = wb[6],  wo1 = wb[22];
                    // row0 uses halo row kh, row1 uses kh+1
                    ai0 = fmaf(h0v[kh],     wi0, ai0); ai0 = fmaf(h1v[kh],     wi1, ai0);
                    af0 = fmaf(h0v[kh],     wf0, af0); af0 = fmaf(h1v[kh],     wf1, af0);
                    ag0 = fmaf(h0v[kh],     wg0, ag0); ag0 = fmaf(h1v[kh],     wg1, ag0);
                    ao0 = fmaf(h0v[kh],     wo0, ao0); ao0 = fmaf(h1v[kh],     wo1, ao0);
                    ai1 = fmaf(h0v[kh + 1], wi0, ai1); ai1 = fmaf(h1v[kh + 1], wi1, ai1);
                    af1 = fmaf(h0v[kh + 1], wf0, af1); af1 = fmaf(h1v[kh + 1], wf1, af1);
                    ag1 = fmaf(h0v[kh + 1], wg0, ag1); ag1 = fmaf(h1v[kh + 1], wg1, ag1);
                    ao1 = fmaf(h0v[kh + 1], wo0, ao1); ao1 = fmaf(h1v[kh + 1], wo1, ao1);
                }
            }
        }

        float gi0 = hsig(ai0), gf0 = hsig(af0), gg0 = ftanh(ag0), go0 = hsig(ao0);
        float gi1 = hsig(ai1), gf1 = hsig(af1), gg1 = ftanh(ag1), go1 = hsig(ao1);
        c0 = gf0 * c0 + gi0 * gg0;
        c1 = gf1 * c1 + gi1 * gg1;

        float* op = out + (size_t)(b * T_ + t) * F_ * HW_ + (size_t)f * HW_
                        + oh0 * W_ + ow;
        op[0]  = go0 * ftanh(c0);
        op[W_] = go1 * ftanh(c1);
    }
}

extern "C" void kernel_launch(void* const* d_in, const int* in_sizes, int n_in,
                              void* d_out, int out_size, void* d_ws, size_t ws_size,
                              hipStream_t stream) {
    const float* x  = (const float*)d_in[0];
    const float* Wx = (const float*)d_in[1];
    const float* Wh = (const float*)d_in[2];
    float* out = (float*)d_out;
    float* xg  = (float*)d_ws;     // 64 MiB

    void* args[] = { (void*)&x, (void*)&Wx, (void*)&Wh, (void*)&out, (void*)&xg };
    hipLaunchCooperativeKernel(reinterpret_cast<void*>(fused_kernel),
                               dim3(512), dim3(256), args, 0, stream);
}

// Round 15
// 346.424 us; speedup vs baseline: 4.5400x; 4.5400x over previous
//
#include <hip/hip_runtime.h>
#include <cmath>

// ConvLSTM, two-phase, multi-launch (cooperative fusion measured 12x slower:
// grid.sync ~90us each on 8 XCDs, R14).
//   Phase 1: xg = conv_same(x[:, ::-1], Wx). Depth-1 A/B register pipeline
//            (deeper spills: R7/R9/R11), NT stores (best total R8), at
//            __launch_bounds__(256,8): body compiled to exactly 64 VGPR at
//            (256,4), so 8 blocks/CU fits -> 2x TLP for latency hiding.
//   Phase 2: 16 sequential F-split step kernels (R9: ~1.1 us/step).
//
// x:  (B=8, T=16, C=16, H=128, W=128) f32
// Wx: (KH=4, KW=2, C=16, O=8) HWIO     idx = kh*256 + kw*128 + c*8 + o
// Wh: (KH=4, KW=2, F=2, O=8)
// out:(B, T, F=2, H, W) f32
// ws: xg (64 MiB, layout [t][b][o][h][w]) + c-state (1 MiB)

constexpr int B_ = 8;
constexpr int T_ = 16;
constexpr int C_ = 16;
constexpr int F_ = 2;
constexpr int O_ = 8;
constexpr int H_ = 128;
constexpr int W_ = 128;
constexpr int HW_ = H_ * W_;
constexpr int KH_ = 4;
constexpr int KW_ = 2;
constexpr int PX_ = 4;

typedef float fv4 __attribute__((ext_vector_type(4)));

__device__ __forceinline__ float hsig(float z) {
    return fminf(fmaxf(0.2f * z + 0.5f, 0.0f), 1.0f);
}

__device__ __forceinline__ float ftanh(float x) {
    float e = __expf(2.0f * x);
    return fmaf(-2.0f, 1.0f / (e + 1.0f), 1.0f);
}

// load the 4 input rows (ih = r0-1 .. r0+2) of one channel plane
template<bool CHECK>
__device__ __forceinline__ void load4(
    const float* __restrict__ xc,   // channel base + ow4
    int r0m1, fv4 a[KH_])
{
    #pragma unroll
    for (int rr = 0; rr < KH_; ++rr) {
        int ih = r0m1 + rr;
        if (CHECK) {
            bool v = (unsigned)ih < (unsigned)H_;
            a[rr] = *reinterpret_cast<const fv4*>(xc + (v ? ih : 0) * W_);
            if (!v) a[rr] = (fv4)0.0f;
        } else {
            a[rr] = *reinterpret_cast<const fv4*>(xc + ih * W_);
        }
    }
}

// accumulate one channel: 4 kh-taps x 2 kw-taps x 8 outputs x 4 px
__device__ __forceinline__ void accum4(
    const float* __restrict__ wc,   // Wx + c*O_
    const fv4 a[KH_], float acc[PX_][O_], bool cval)
{
    #pragma unroll
    for (int kh = 0; kh < KH_; ++kh) {
        float x4 = __shfl_down(a[kh].x, 1, 64);   // lane q+1's x0 = px ow4+4
        x4 = cval ? x4 : 0.0f;                    // q=31 wrap masked
        const float* wp = wc + kh * (KW_ * C_ * O_);
        #pragma unroll
        for (int o = 0; o < O_; ++o) {
            float w0 = wp[o];              // kw = 0 (uniform -> SGPR)
            float w1 = wp[C_ * O_ + o];    // kw = 1
            acc[0][o] = fmaf(a[kh].x, w0, acc[0][o]);
            acc[1][o] = fmaf(a[kh].y, w0, acc[1][o]);
            acc[2][o] = fmaf(a[kh].z, w0, acc[2][o]);
            acc[3][o] = fmaf(a[kh].w, w0, acc[3][o]);
            acc[0][o] = fmaf(a[kh].y, w1, acc[0][o]);
            acc[1][o] = fmaf(a[kh].z, w1, acc[1][o]);
            acc[2][o] = fmaf(a[kh].w, w1, acc[2][o]);
            acc[3][o] = fmaf(x4,      w1, acc[3][o]);
        }
    }
}

// depth-1 software pipeline over channels, 2 named buffers (A/B)
template<bool CHECK>
__device__ __forceinline__ void conv_pipe(
    const float* __restrict__ xb,   // image base + ow4
    const float* __restrict__ Wx,
    int r0m1, bool cval, float acc[PX_][O_])
{
    fv4 A[KH_], Bv[KH_];
    load4<CHECK>(xb, r0m1, A);
    #pragma unroll 1
    for (int cc = 0; cc < C_ - 2; cc += 2) {
        load4<CHECK>(xb + (cc + 1) * HW_, r0m1, Bv);
        accum4(Wx + cc * O_, A, acc, cval);
        load4<CHECK>(xb + (cc + 2) * HW_, r0m1, A);
        accum4(Wx + (cc + 1) * O_, Bv, acc, cval);
    }
    load4<CHECK>(xb + (C_ - 1) * HW_, r0m1, Bv);
    accum4(Wx + (C_ - 2) * O_, A, acc, cval);
    accum4(Wx + (C_ - 1) * O_, Bv, acc, cval);
}

// grid: 2048 blocks x 256 thr; block = 8-row slab of one (b,t) image;
// thread = 4 w-pixels, all 8 gate chans. 8 blocks/CU target.
__global__ __launch_bounds__(256, 8) void xg_kernel(
    const float* __restrict__ x,
    const float* __restrict__ Wx,
    float* __restrict__ xg)
{
    // XCD-chunked swizzle (2048 % 8 == 0 -> bijective)
    int wid = (blockIdx.x & 7) * 256 + (blockIdx.x >> 3);

    int bt   = wid >> 4;             // 16 blocks per (b,t)
    int slab = wid & 15;

    int tid  = threadIdx.x;
    int oh_l = tid >> 5;             // 0..7 local row
    int q    = tid & 31;
    int ow4  = q << 2;

    int r0 = slab * 8 + oh_l;

    int b    = bt >> 4;
    int trev = bt & 15;
    int t    = 15 - trev;

    const float* xb = x + (size_t)bt * C_ * HW_ + ow4;
    bool cval = ow4 < (W_ - 4);

    float acc[PX_][O_];
    #pragma unroll
    for (int p = 0; p < PX_; ++p)
        #pragma unroll
        for (int o = 0; o < O_; ++o) acc[p][o] = 0.0f;

    // rows touched: r0-1 .. r0+2; interior slabs 1..14 are select-free
    if (slab >= 1 && slab <= 14) {
        conv_pipe<false>(xb, Wx, r0 - 1, cval, acc);
    } else {
        conv_pipe<true>(xb, Wx, r0 - 1, cval, acc);
    }

    float* dst = xg + (size_t)(t * B_ + b) * O_ * HW_ + r0 * W_ + ow4;
    #pragma unroll
    for (int o = 0; o < O_; ++o) {
        fv4 s;
        s.x = acc[0][o]; s.y = acc[1][o]; s.z = acc[2][o]; s.w = acc[3][o];
        __builtin_nontemporal_store(s, reinterpret_cast<fv4*>(dst + o * HW_));
    }
}

// ---------------- Phase 2: sequential LSTM step (F-split) ----------------
// grid: 1024 blocks (= B*H) x 256 thr. Block = one image row of one b.
// tid 0..127 -> f=0 for 128 pixels; tid 128..255 -> f=1 same pixels.
// f is wave-uniform -> weight loads stay scalar.
__global__ __launch_bounds__(256) void step_kernel(
    const float* __restrict__ xg,
    const float* __restrict__ Wh,
    float* __restrict__ out,
    float* __restrict__ cbuf,
    int t)
{
    int tid = threadIdx.x;
    int f   = tid >> 7;              // 0 or 1 (wave-uniform)
    int ow  = tid & 127;
    int oh  = blockIdx.x & 127;
    int b   = blockIdx.x >> 7;
    int pix = oh * W_ + ow;

    // gate accumulators start from xg_t (chans: i=f, f=2+f, g=4+f, o=6+f)
    const float* xgp = xg + ((size_t)(t * B_ + b) * O_ + f) * HW_ + pix;
    float a_i = xgp[0];
    float a_f = xgp[2 * HW_];
    float a_g = xgp[4 * HW_];
    float a_o = xgp[6 * HW_];

    bool cv  = (ow + 1) < W_;
    int  co1 = cv ? 1 : 0;

    if (t > 0) {
        const float* hs = out + (size_t)(b * T_ + (t - 1)) * F_ * HW_;
        #pragma unroll
        for (int kh = 0; kh < KH_; ++kh) {
            int ih  = oh + kh - 1;
            bool rv = (unsigned)ih < (unsigned)H_;
            int ihc = rv ? ih : 0;
            const float* hrow = hs + ihc * W_ + ow;
            #pragma unroll
            for (int fin = 0; fin < F_; ++fin) {
                float h0 = hrow[fin * HW_];
                float h1 = hrow[fin * HW_ + co1];
                h0 = rv ? h0 : 0.0f;
                h1 = (rv && cv) ? h1 : 0.0f;
                // Wh idx = kh*32 + kw*16 + fin*8 + o; o = {f, 2+f, 4+f, 6+f}
                const float* wb = Wh + kh * (KW_ * F_ * O_) + fin * O_ + f;
                a_i = fmaf(h0, wb[0],  a_i);  a_i = fmaf(h1, wb[16], a_i);
                a_f = fmaf(h0, wb[2],  a_f);  a_f = fmaf(h1, wb[18], a_f);
                a_g = fmaf(h0, wb[4],  a_g);  a_g = fmaf(h1, wb[20], a_g);
                a_o = fmaf(h0, wb[6],  a_o);  a_o = fmaf(h1, wb[22], a_o);
            }
        }
    }

    float gi = hsig(a_i);
    float gf = hsig(a_f);
    float gg = ftanh(a_g);
    float go = hsig(a_o);

    size_t cidx = (size_t)b * F_ * HW_ + (size_t)f * HW_ + pix;
    float cp = (t > 0) ? cbuf[cidx] : 0.0f;
    float cn = gf * cp + gi * gg;
    cbuf[cidx] = cn;

    out[(size_t)(b * T_ + t) * F_ * HW_ + (size_t)f * HW_ + pix] = go * ftanh(cn);
}

extern "C" void kernel_launch(void* const* d_in, const int* in_sizes, int n_in,
                              void* d_out, int out_size, void* d_ws, size_t ws_size,
                              hipStream_t stream) {
    const float* x  = (const float*)d_in[0];
    const float* Wx = (const float*)d_in[1];
    const float* Wh = (const float*)d_in[2];
    float* out  = (float*)d_out;

    float* xg   = (float*)d_ws;                                            // 64 MiB
    float* cbuf = (float*)((char*)d_ws + (size_t)64 * 1024 * 1024 + 1024); // 1 MiB

    int xg_blocks = (B_ * T_ * HW_ / PX_) / 256;   // 2048
    xg_kernel<<<xg_blocks, 256, 0, stream>>>(x, Wx, xg);

    int step_blocks = B_ * H_;                     // 1024
    for (int t = 0; t < T_; ++t) {
        step_kernel<<<step_blocks, 256, 0, stream>>>(xg, Wh, out, cbuf, t);
    }
}

// Round 16
// 154.489 us; speedup vs baseline: 10.1805x; 2.2424x over previous
//
#include <hip/hip_runtime.h>
#include <cmath>

// ConvLSTM, two-phase, multi-launch (coop grid.sync ~90us each — dead end, R14).
//   Phase 1: xg = conv_same(x[:, ::-1], Wx). PX=2 tile: live set ~45 VGPR
//            fits the 64-VGPR / 8-waves-per-SIMD budget -> 2x TLP vs the
//            PX=4 tile (which is capped at 4 waves/SIMD; all deeper/denser
//            variants spilled: R7/R9/R11/R15). Depth-1 A/B named-buffer
//            pipeline over c; kw=1 tail via __shfl_down only (no tail loads);
//            NT stores.
//   Phase 2: 16 sequential step kernels — R8's exact config (best total).
//
// x:  (B=8, T=16, C=16, H=128, W=128) f32
// Wx: (KH=4, KW=2, C=16, O=8) HWIO     idx = kh*256 + kw*128 + c*8 + o
// Wh: (KH=4, KW=2, F=2, O=8)
// out:(B, T, F=2, H, W) f32
// ws: xg (64 MiB, layout [t][b][o][h][w]) + c-state (1 MiB)

constexpr int B_ = 8;
constexpr int T_ = 16;
constexpr int C_ = 16;
constexpr int F_ = 2;
constexpr int O_ = 8;
constexpr int H_ = 128;
constexpr int W_ = 128;
constexpr int HW_ = H_ * W_;
constexpr int KH_ = 4;
constexpr int KW_ = 2;

typedef float fv2 __attribute__((ext_vector_type(2)));
typedef float fv4 __attribute__((ext_vector_type(4)));

__device__ __forceinline__ float hsig(float z) {
    return fminf(fmaxf(0.2f * z + 0.5f, 0.0f), 1.0f);
}

__device__ __forceinline__ float ftanh(float x) {
    float e = __expf(2.0f * x);
    return fmaf(-2.0f, 1.0f / (e + 1.0f), 1.0f);
}

// load the 4 input rows (ih = r0-1 .. r0+2) of one channel plane, 2 px each
template<bool CHECK>
__device__ __forceinline__ void load4(
    const float* __restrict__ xc,   // channel base + ow2
    int r0m1, fv2 a[KH_])
{
    #pragma unroll
    for (int rr = 0; rr < KH_; ++rr) {
        int ih = r0m1 + rr;
        if (CHECK) {
            bool v = (unsigned)ih < (unsigned)H_;
            a[rr] = *reinterpret_cast<const fv2*>(xc + (v ? ih : 0) * W_);
            if (!v) a[rr] = (fv2)0.0f;
        } else {
            a[rr] = *reinterpret_cast<const fv2*>(xc + ih * W_);
        }
    }
}

// accumulate one channel: 4 kh x 2 kw x 8 o x 2 px = 128 fma
__device__ __forceinline__ void accum2(
    const float* __restrict__ wc,   // Wx + c*O_
    const fv2 a[KH_], float acc[2][O_], bool cval)
{
    #pragma unroll
    for (int kh = 0; kh < KH_; ++kh) {
        float x2 = __shfl_down(a[kh].x, 1, 64);   // lane q+1's x0 = px ow2+2
        x2 = cval ? x2 : 0.0f;                    // q=63 wrap masked
        const float* wp = wc + kh * (KW_ * C_ * O_);
        #pragma unroll
        for (int o = 0; o < O_; ++o) {
            float w0 = wp[o];              // kw = 0 (uniform -> SGPR)
            float w1 = wp[C_ * O_ + o];    // kw = 1
            acc[0][o] = fmaf(a[kh].x, w0, acc[0][o]);
            acc[1][o] = fmaf(a[kh].y, w0, acc[1][o]);
            acc[0][o] = fmaf(a[kh].y, w1, acc[0][o]);
            acc[1][o] = fmaf(x2,      w1, acc[1][o]);
        }
    }
}

// depth-1 software pipeline over channels, 2 named buffers (A/B)
template<bool CHECK>
__device__ __forceinline__ void conv_pipe(
    const float* __restrict__ xb,   // image base + ow2
    const float* __restrict__ Wx,
    int r0m1, bool cval, float acc[2][O_])
{
    fv2 A[KH_], Bv[KH_];
    load4<CHECK>(xb, r0m1, A);
    #pragma unroll 1
    for (int cc = 0; cc < C_ - 2; cc += 2) {
        load4<CHECK>(xb + (cc + 1) * HW_, r0m1, Bv);
        accum2(Wx + cc * O_, A, acc, cval);
        load4<CHECK>(xb + (cc + 2) * HW_, r0m1, A);
        accum2(Wx + (cc + 1) * O_, Bv, acc, cval);
    }
    load4<CHECK>(xb + (C_ - 1) * HW_, r0m1, Bv);
    accum2(Wx + (C_ - 2) * O_, A, acc, cval);
    accum2(Wx + (C_ - 1) * O_, Bv, acc, cval);
}

// grid: 4096 blocks x 256 thr; block = 4-row slab of one (b,t) image;
// thread = 2 w-pixels (full wave = one row), all 8 gate chans.
__global__ __launch_bounds__(256, 8) void xg_kernel(
    const float* __restrict__ x,
    const float* __restrict__ Wx,
    float* __restrict__ xg)
{
    // XCD-chunked swizzle (4096 % 8 == 0 -> bijective)
    int wid = (blockIdx.x & 7) * 512 + (blockIdx.x >> 3);

    int bt   = wid >> 5;             // 32 blocks per (b,t)
    int slab = wid & 31;

    int tid   = threadIdx.x;
    int row_l = tid >> 6;            // 0..3 local row (one wave per row)
    int q     = tid & 63;
    int ow2   = q << 1;

    int r0 = slab * 4 + row_l;

    int b    = bt >> 4;
    int trev = bt & 15;
    int t    = 15 - trev;

    const float* xb = x + (size_t)bt * C_ * HW_ + ow2;
    bool cval = ow2 < (W_ - 2);      // q < 63

    float acc[2][O_];
    #pragma unroll
    for (int p = 0; p < 2; ++p)
        #pragma unroll
        for (int o = 0; o < O_; ++o) acc[p][o] = 0.0f;

    // rows touched: r0-1 .. r0+2; interior slabs 1..30 are select-free
    if (slab >= 1 && slab <= 30) {
        conv_pipe<false>(xb, Wx, r0 - 1, cval, acc);
    } else {
        conv_pipe<true>(xb, Wx, r0 - 1, cval, acc);
    }

    float* dst = xg + (size_t)(t * B_ + b) * O_ * HW_ + r0 * W_ + ow2;
    #pragma unroll
    for (int o = 0; o < O_; ++o) {
        fv2 s;
        s.x = acc[0][o]; s.y = acc[1][o];
        __builtin_nontemporal_store(s, reinterpret_cast<fv2*>(dst + o * HW_));
    }
}

// ---------------- Phase 2: sequential LSTM step (R8 config) ----------------
__global__ __launch_bounds__(256) void step_kernel(
    const float* __restrict__ xg,
    const float* __restrict__ Wh,
    float* __restrict__ out,
    float* __restrict__ cbuf,
    int t)
{
    int gid = blockIdx.x * 256 + threadIdx.x;   // B*HW = 131072
    int b   = gid >> 14;
    int pix = gid & (HW_ - 1);
    int oh  = pix >> 7;
    int ow  = pix & (W_ - 1);

    const float* xgp = xg + (size_t)(t * B_ + b) * O_ * HW_ + pix;
    float acc[O_];
    #pragma unroll
    for (int o = 0; o < O_; ++o)
        acc[o] = __builtin_nontemporal_load(xgp + o * HW_);

    bool cv  = (ow + 1) < W_;
    int  co1 = cv ? 1 : 0;

    if (t > 0) {
        const float* hs = out + (size_t)(b * T_ + (t - 1)) * F_ * HW_;
        #pragma unroll
        for (int kh = 0; kh < KH_; ++kh) {
            int ih  = oh + kh - 1;
            bool rv = (unsigned)ih < (unsigned)H_;
            int ihc = rv ? ih : 0;
            const float* hrow = hs + ihc * W_ + ow;
            const float* wb   = Wh + kh * (KW_ * F_ * O_);
            #pragma unroll
            for (int f = 0; f < F_; ++f) {
                float h0 = hrow[f * HW_];
                float h1 = hrow[f * HW_ + co1];
                h0 = rv ? h0 : 0.0f;
                h1 = (rv && cv) ? h1 : 0.0f;
                #pragma unroll
                for (int o = 0; o < O_; ++o) {
                    acc[o] = fmaf(h0, wb[f * O_ + o], acc[o]);
                    acc[o] = fmaf(h1, wb[F_ * O_ + f * O_ + o], acc[o]);
                }
            }
        }
    }

    size_t cidx = (size_t)b * F_ * HW_ + pix;
    float cp0 = 0.0f, cp1 = 0.0f;
    if (t > 0) { cp0 = cbuf[cidx]; cp1 = cbuf[cidx + HW_]; }

    float gi0 = hsig(acc[0]);
    float gi1 = hsig(acc[1]);
    float gf0 = hsig(acc[2]);
    float gf1 = hsig(acc[3]);
    float gg0 = ftanh(acc[4]);
    float gg1 = ftanh(acc[5]);
    float go0 = hsig(acc[6]);
    float go1 = hsig(acc[7]);

    float cn0 = gf0 * cp0 + gi0 * gg0;
    float cn1 = gf1 * cp1 + gi1 * gg1;
    cbuf[cidx]       = cn0;
    cbuf[cidx + HW_] = cn1;

    size_t oidx = (size_t)(b * T_ + t) * F_ * HW_ + pix;
    out[oidx]       = go0 * ftanh(cn0);
    out[oidx + HW_] = go1 * ftanh(cn1);
}

extern "C" void kernel_launch(void* const* d_in, const int* in_sizes, int n_in,
                              void* d_out, int out_size, void* d_ws, size_t ws_size,
                              hipStream_t stream) {
    const float* x  = (const float*)d_in[0];
    const float* Wx = (const float*)d_in[1];
    const float* Wh = (const float*)d_in[2];
    float* out  = (float*)d_out;

    float* xg   = (float*)d_ws;                                            // 64 MiB
    float* cbuf = (float*)((char*)d_ws + (size_t)64 * 1024 * 1024 + 1024); // 1 MiB

    int xg_blocks = (B_ * T_ * HW_ / 2) / 256;     // 4096
    xg_kernel<<<xg_blocks, 256, 0, stream>>>(x, Wx, xg);

    int blocks = (B_ * HW_) / 256;                 // 512
    for (int t = 0; t < T_; ++t) {
        step_kernel<<<blocks, 256, 0, stream>>>(xg, Wh, out, cbuf, t);
    }
}